// Round 1
// baseline (351.211 us; speedup 1.0000x reference)
//
#include <hip/hip_runtime.h>
#include <hip/hip_bf16.h>

#define A_TOT 8400
#define NB 32
#define NG 16
#define NC 80

// ---------- device helpers ----------

__device__ inline float sigm(float x) { return 1.0f / (1.0f + expf(-x)); }

__device__ inline float bce0(float x) {  // bce(x, t=0) = max(x,0) + log1p(exp(-|x|))
    return fmaxf(x, 0.0f) + log1pf(expf(-fabsf(x)));
}

__device__ inline float iou_cxcywh(float acx, float acy, float aw, float ah,
                                   float bcx, float bcy, float bw, float bh) {
    float tlx = fmaxf(acx - aw * 0.5f, bcx - bw * 0.5f);
    float tly = fmaxf(acy - ah * 0.5f, bcy - bh * 0.5f);
    float brx = fminf(acx + aw * 0.5f, bcx + bw * 0.5f);
    float bry = fminf(acy + ah * 0.5f, bcy + bh * 0.5f);
    float w = fmaxf(brx - tlx, 0.0f);
    float h = fmaxf(bry - tly, 0.0f);
    float inter = w * h;
    return inter / (aw * ah + bw * bh - inter + 1e-16f);
}

// cost for (g, a); m = umask word (bit16 = union, bits0..15 = inter per g)
__device__ inline float cost_at(float iou, float d, float sp, unsigned m, int g) {
    if (!((m >> 16) & 1u)) return 1e15f;
    float c = -(d + sp) + 3.0f * (-logf(iou + 1e-8f));
    if (!((m >> g) & 1u)) c += 100000.0f;
    return c;
}

__device__ inline unsigned long long umax64(unsigned long long a, unsigned long long b) {
    return a > b ? a : b;
}
__device__ inline unsigned long long umin64(unsigned long long a, unsigned long long b) {
    return a < b ? a : b;
}

// resolve anchor index -> level base / hw / HW / W / stride
__device__ inline const float* lvl_base(int a, int b, const float* p8, const float* p16,
                                        const float* p32, int& hw, int& HW, int& W, float& s) {
    if (a < 6400) { hw = a;        HW = 6400; W = 80; s = 8.0f;  return p8  + (size_t)b * 85 * 6400; }
    if (a < 8000) { hw = a - 6400; HW = 1600; W = 40; s = 16.0f; return p16 + (size_t)b * 85 * 1600; }
    { hw = a - 8000; HW = 400; W = 20; s = 32.0f; return p32 + (size_t)b * 85 * 400; }
}

// ---------- kernel 0: zero accumulators ----------
__global__ void k0_zero(float* acc) {
    if (threadIdx.x < 8) acc[threadIdx.x] = 0.0f;
}

// ---------- kernel 1: decode + per-anchor stats ----------
// per (b,a): pbox float4, conf logit, sum log1mp, sum bce0(cls), umask,
//            dval[g] = logp - log1mp at class gt_cls[b,g]; global sum of bce0(conf)
__global__ __launch_bounds__(256) void k1_decode(
    const float* __restrict__ p8, const float* __restrict__ p16, const float* __restrict__ p32,
    const float* __restrict__ gtb, const int* __restrict__ gtc,
    float4* __restrict__ pbox, float* __restrict__ dval, float* __restrict__ sl1p,
    float* __restrict__ s0cls, float* __restrict__ confw, unsigned* __restrict__ umask,
    float* __restrict__ acc) {
    int gid = blockIdx.x * 256 + threadIdx.x;
    float bce0_conf = 0.0f;
    if (gid < NB * A_TOT) {
        int b = gid / A_TOT;
        int a = gid - b * A_TOT;
        int hw, HW, W;
        float s;
        const float* base = lvl_base(a, b, p8, p16, p32, hw, HW, W, s);

        float tx = base[hw], ty = base[HW + hw];
        float tw = base[2 * HW + hw], th = base[3 * HW + hw];
        float cf = base[4 * HW + hw];
        int gx = hw % W, gy = hw / W;
        float pcx = (tx + (float)gx) * s;
        float pcy = (ty + (float)gy) * s;
        float pw = expf(tw) * s;
        float ph = expf(th) * s;

        float sc = sigm(cf);
        bce0_conf = bce0(cf);

        float suml1p = 0.0f, s0 = 0.0f;
        for (int c = 0; c < NC; c++) {
            float x = base[(5 + c) * HW + hw];
            float sx = sigm(x);
            float pr = sqrtf(sx * sc);
            float l1p = fmaxf(logf(fmaxf(1.0f - pr, 1e-12f)), -100.0f);
            suml1p += l1p;
            s0 += bce0(x);
        }

        // dval per gt
        for (int g = 0; g < NG; g++) {
            int c = gtc[b * NG + g];
            float x = base[(5 + c) * HW + hw];
            float sx = sigm(x);
            float pr = sqrtf(sx * sc);
            float lp = fmaxf(logf(fmaxf(pr, 1e-12f)), -100.0f);
            float l1p = fmaxf(logf(fmaxf(1.0f - pr, 1e-12f)), -100.0f);
            dval[((size_t)(b * NG + g)) * A_TOT + a] = lp - l1p;
        }

        // union / inter masks
        float xc = ((float)gx + 0.5f) * s;
        float yc = ((float)gy + 0.5f) * s;
        unsigned m = 0;
        bool uni = false;
        float r = 2.5f * s;
        for (int g = 0; g < NG; g++) {
            float gcx = gtb[(b * NG + g) * 4 + 0];
            float gcy = gtb[(b * NG + g) * 4 + 1];
            float gw  = gtb[(b * NG + g) * 4 + 2];
            float gh  = gtb[(b * NG + g) * 4 + 3];
            bool ib = (xc > gcx - gw * 0.5f) && (gcx + gw * 0.5f > xc) &&
                      (yc > gcy - gh * 0.5f) && (gcy + gh * 0.5f > yc);
            bool im = (xc > gcx - r) && (gcx + r > xc) &&
                      (yc > gcy - r) && (gcy + r > yc);
            uni |= (ib || im);
            if (ib && im) m |= (1u << g);
        }
        if (uni) m |= (1u << 16);

        size_t i = (size_t)b * A_TOT + a;
        pbox[i] = make_float4(pcx, pcy, pw, ph);
        confw[i] = cf;
        sl1p[i] = suml1p;
        s0cls[i] = s0;
        umask[i] = m;
    }
    // wave-reduce bce0(conf) and atomically add
    float v = bce0_conf;
    for (int off = 32; off; off >>= 1) v += __shfl_down(v, off, 64);
    if ((threadIdx.x & 63) == 0) atomicAdd(&acc[0], v);
}

// ---------- kernel 2: per-(b,g) cost row + dual top-10 selection ----------
__global__ __launch_bounds__(256) void k2_assign(
    const float* __restrict__ gtb, const float4* __restrict__ pbox,
    const float* __restrict__ dval, const float* __restrict__ sl1p,
    const unsigned* __restrict__ umask, int* __restrict__ sel, int* __restrict__ nsel) {
    __shared__ float buf[A_TOT];
    __shared__ unsigned long long rk[256];
    int blk = blockIdx.x;            // b*16+g
    int b = blk >> 4, g = blk & 15;
    int tid = threadIdx.x;

    float gcx = gtb[blk * 4 + 0], gcy = gtb[blk * 4 + 1];
    float gw = gtb[blk * 4 + 2],  gh = gtb[blk * 4 + 3];

    // ---- pass A: masked iou row ----
    for (int a = tid; a < A_TOT; a += 256) {
        float4 pb = pbox[(size_t)b * A_TOT + a];
        float iou = iou_cxcywh(gcx, gcy, gw, gh, pb.x, pb.y, pb.z, pb.w);
        unsigned m = umask[(size_t)b * A_TOT + a];
        buf[a] = ((m >> 16) & 1u) ? iou : 0.0f;
    }
    __syncthreads();

    // ---- selection 1: sum of top-10 iou (descending order) ----
    float ksum = 0.0f;
    for (int rr = 0; rr < 10; rr++) {
        unsigned long long best = 0ull;
        for (int a = tid; a < A_TOT; a += 256) {
            unsigned long long k = ((unsigned long long)__float_as_uint(buf[a]) << 32) | (unsigned)a;
            if (k > best) best = k;
        }
        rk[tid] = best;
        __syncthreads();
        for (int s2 = 128; s2 > 0; s2 >>= 1) {
            if (tid < s2) rk[tid] = umax64(rk[tid], rk[tid + s2]);
            __syncthreads();
        }
        unsigned long long w = rk[0];
        ksum += __uint_as_float((unsigned)(w >> 32));
        int idx = (int)(w & 0xffffffffu);
        if (tid == 0) buf[idx] = 0.0f;   // consume (re-pick of zeros adds 0 -> harmless)
        __syncthreads();
    }
    int dynk = (int)ksum;               // truncation matches astype(int32)
    if (dynk < 1) dynk = 1;
    if (dynk > 10) dynk = 10;

    // ---- pass B: cost row ----
    for (int a = tid; a < A_TOT; a += 256) {
        float4 pb = pbox[(size_t)b * A_TOT + a];
        float iou = iou_cxcywh(gcx, gcy, gw, gh, pb.x, pb.y, pb.z, pb.w);
        unsigned m = umask[(size_t)b * A_TOT + a];
        float d = dval[(size_t)blk * A_TOT + a];
        float sp = sl1p[(size_t)b * A_TOT + a];
        buf[a] = cost_at(iou, d, sp, m, g);
    }
    __syncthreads();

    // ---- selection 2: 10 smallest costs (ascending), lowest-index tie-break ----
    for (int rr = 0; rr < 10; rr++) {
        unsigned long long best = 0xFFFFFFFFFFFFFFFFull;
        for (int a = tid; a < A_TOT; a += 256) {
            unsigned long long k = ((unsigned long long)__float_as_uint(buf[a]) << 32) | (unsigned)a;
            if (k < best) best = k;
        }
        rk[tid] = best;
        __syncthreads();
        for (int s2 = 128; s2 > 0; s2 >>= 1) {
            if (tid < s2) rk[tid] = umin64(rk[tid], rk[tid + s2]);
            __syncthreads();
        }
        unsigned long long w = rk[0];
        int idx = (int)(w & 0xffffffffu);
        if (tid == 0) {
            sel[blk * 10 + rr] = idx;
            buf[idx] = __uint_as_float(0x7F800000u);  // +inf consume
        }
        __syncthreads();
    }
    if (tid == 0) nsel[blk] = dynk;
}

// ---------- kernel 3: per-batch conflict resolution + fused loss partials ----------
__global__ __launch_bounds__(256) void k3_resolve(
    const float* __restrict__ gtb, const int* __restrict__ gtc,
    const float4* __restrict__ pbox, const float* __restrict__ dval,
    const float* __restrict__ sl1p, const unsigned* __restrict__ umask,
    const float* __restrict__ confw, const float* __restrict__ s0cls,
    const int* __restrict__ sel, const int* __restrict__ nsel,
    const float* __restrict__ p8, const float* __restrict__ p16, const float* __restrict__ p32,
    float* __restrict__ acc) {
    __shared__ unsigned tag[A_TOT];
    __shared__ float gb[NG * 4];
    __shared__ int gc[NG];
    __shared__ float red[256];
    int b = blockIdx.x, tid = threadIdx.x;

    for (int a = tid; a < A_TOT; a += 256) tag[a] = 0;
    if (tid < NG * 4) gb[tid] = gtb[b * NG * 4 + tid];
    if (tid < NG) gc[tid] = gtc[b * NG + tid];
    __syncthreads();

    if (tid < NG * 10) {
        int g = tid / 10, k = tid % 10;
        if (k < nsel[b * NG + g]) {
            int a = sel[(b * NG + g) * 10 + k];
            atomicAdd(&tag[a], 0x10000u + (unsigned)(g + 1));
        }
    }
    __syncthreads();

    float lbox = 0.0f, lconfc = 0.0f, lcls = 0.0f, nfg = 0.0f;
    for (int a = tid; a < A_TOT; a += 256) {
        unsigned t = tag[a];
        unsigned cnt = t >> 16;
        if (!cnt) continue;
        float4 pb = pbox[(size_t)b * A_TOT + a];
        int gs;
        if (cnt == 1) {
            gs = (int)(t & 0xffffu) - 1;
        } else {
            // argmin over all G of cost (first-min => lowest g on ties)
            unsigned m = umask[(size_t)b * A_TOT + a];
            float sp = sl1p[(size_t)b * A_TOT + a];
            float bc = 3.402823466e38f;
            gs = 0;
            for (int g = 0; g < NG; g++) {
                float iou = iou_cxcywh(gb[g * 4], gb[g * 4 + 1], gb[g * 4 + 2], gb[g * 4 + 3],
                                       pb.x, pb.y, pb.z, pb.w);
                float d = dval[((size_t)(b * NG + g)) * A_TOT + a];
                float c = cost_at(iou, d, sp, m, g);
                if (c < bc) { bc = c; gs = g; }
            }
        }
        float miou = iou_cxcywh(gb[gs * 4], gb[gs * 4 + 1], gb[gs * 4 + 2], gb[gs * 4 + 3],
                                pb.x, pb.y, pb.z, pb.w);
        int cid = gc[gs];
        int hw, HW, W;
        float s;
        const float* base = lvl_base(a, b, p8, p16, p32, hw, HW, W, s);
        float xcid = base[(5 + cid) * HW + hw];

        lbox += 1.0f - miou * miou;
        lconfc -= confw[(size_t)b * A_TOT + a];
        lcls += s0cls[(size_t)b * A_TOT + a] - xcid * miou;
        nfg += 1.0f;
    }

    // block reduce the four partials
    float vals[4] = {lbox, lconfc, lcls, nfg};
    for (int i = 0; i < 4; i++) {
        red[tid] = vals[i];
        __syncthreads();
        for (int s2 = 128; s2 > 0; s2 >>= 1) {
            if (tid < s2) red[tid] += red[tid + s2];
            __syncthreads();
        }
        if (tid == 0) atomicAdd(&acc[1 + i], red[0]);
        __syncthreads();
    }
}

// ---------- kernel 4: final scalar ----------
__global__ void k4_final(const float* __restrict__ acc, float* __restrict__ out) {
    if (threadIdx.x == 0 && blockIdx.x == 0) {
        float nfg = acc[4];
        if (nfg < 1.0f) nfg = 1.0f;
        // loss = (5*loss_box + loss_conf + loss_cls)/n_fg
        out[0] = (5.0f * acc[1] + (acc[0] + acc[2]) + acc[3]) / nfg;
    }
}

// ---------- launch ----------
extern "C" void kernel_launch(void* const* d_in, const int* in_sizes, int n_in,
                              void* d_out, int out_size, void* d_ws, size_t ws_size,
                              hipStream_t stream) {
    const float* p8  = (const float*)d_in[0];
    const float* p16 = (const float*)d_in[1];
    const float* p32 = (const float*)d_in[2];
    const float* gtb = (const float*)d_in[3];
    const int*   gtc = (const int*)d_in[4];

    char* w = (char*)d_ws;
    float4* pbox = (float4*)w;                 w += (size_t)NB * A_TOT * sizeof(float4);
    float* dval  = (float*)w;                  w += (size_t)NB * NG * A_TOT * sizeof(float);
    float* sl1p  = (float*)w;                  w += (size_t)NB * A_TOT * sizeof(float);
    float* s0c   = (float*)w;                  w += (size_t)NB * A_TOT * sizeof(float);
    float* conf  = (float*)w;                  w += (size_t)NB * A_TOT * sizeof(float);
    unsigned* um = (unsigned*)w;               w += (size_t)NB * A_TOT * sizeof(unsigned);
    int* sel     = (int*)w;                    w += (size_t)NB * NG * 10 * sizeof(int);
    int* nsel    = (int*)w;                    w += (size_t)NB * NG * sizeof(int);
    float* acc   = (float*)w;

    k0_zero<<<1, 64, 0, stream>>>(acc);
    k1_decode<<<(NB * A_TOT + 255) / 256, 256, 0, stream>>>(
        p8, p16, p32, gtb, gtc, pbox, dval, sl1p, s0c, conf, um, acc);
    k2_assign<<<NB * NG, 256, 0, stream>>>(gtb, pbox, dval, sl1p, um, sel, nsel);
    k3_resolve<<<NB, 256, 0, stream>>>(gtb, gtc, pbox, dval, sl1p, um, conf, s0c,
                                       sel, nsel, p8, p16, p32, acc);
    k4_final<<<1, 64, 0, stream>>>(acc, (float*)d_out);
}

// Round 2
// 248.920 us; speedup vs baseline: 1.4109x; 1.4109x over previous
//
#include <hip/hip_runtime.h>
#include <hip/hip_bf16.h>

#define A_TOT 8400
#define NB 32
#define NG 16
#define NC 80

#define L2E 1.44269504088896340736f
#define LN2 0.69314718055994530942f

// ---------- fast native transcendentals ----------
__device__ inline float fexp2(float x) { return __builtin_amdgcn_exp2f(x); }
__device__ inline float flog2(float x) { return __builtin_amdgcn_logf(x); }
__device__ inline float frcp(float x)  { return __builtin_amdgcn_rcpf(x); }
__device__ inline float fsqrtf_(float x) { return __builtin_amdgcn_sqrtf(x); }

__device__ inline float iou_cxcywh(float acx, float acy, float aw, float ah,
                                   float bcx, float bcy, float bw, float bh) {
    float tlx = fmaxf(acx - aw * 0.5f, bcx - bw * 0.5f);
    float tly = fmaxf(acy - ah * 0.5f, bcy - bh * 0.5f);
    float brx = fminf(acx + aw * 0.5f, bcx + bw * 0.5f);
    float bry = fminf(acy + ah * 0.5f, bcy + bh * 0.5f);
    float w = fmaxf(brx - tlx, 0.0f);
    float h = fmaxf(bry - tly, 0.0f);
    float inter = w * h;
    return inter / (aw * ah + bw * bh - inter + 1e-16f);
}

// cost for (g, a); m = umask word (bit16 = union, bits0..15 = inter per g)
__device__ inline float cost_fast(float iou, float d, float sp, unsigned m, int g) {
    if (!((m >> 16) & 1u)) return 1e15f;
    float c = -(d + sp) - 3.0f * LN2 * flog2(iou + 1e-8f);
    if (!((m >> g) & 1u)) c += 100000.0f;
    return c;
}

__device__ inline unsigned long long umax64(unsigned long long a, unsigned long long b) {
    return a > b ? a : b;
}
__device__ inline unsigned long long umin64(unsigned long long a, unsigned long long b) {
    return a < b ? a : b;
}

// resolve anchor index -> level base / hw / HW / W / stride
__device__ inline const float* lvl_base(int a, int b, const float* p8, const float* p16,
                                        const float* p32, int& hw, int& HW, int& W, float& s) {
    if (a < 6400) { hw = a;        HW = 6400; W = 80; s = 8.0f;  return p8  + (size_t)b * 85 * 6400; }
    if (a < 8000) { hw = a - 6400; HW = 1600; W = 40; s = 16.0f; return p16 + (size_t)b * 85 * 1600; }
    { hw = a - 8000; HW = 400; W = 20; s = 32.0f; return p32 + (size_t)b * 85 * 400; }
}

// ---------- kernel 0: zero accumulators ----------
__global__ void k0_zero(float* acc) {
    if (threadIdx.x < 8) acc[threadIdx.x] = 0.0f;
}

// ---------- kernel 1: decode + per-anchor stats ----------
// grid = dim3(33, NB): b is block-uniform -> gt loads are scalar.
__global__ __launch_bounds__(256) void k1_decode(
    const float* __restrict__ p8, const float* __restrict__ p16, const float* __restrict__ p32,
    const float* __restrict__ gtb, const int* __restrict__ gtc,
    float4* __restrict__ pbox, float* __restrict__ dval, float* __restrict__ sl1p,
    float* __restrict__ s0cls, float* __restrict__ confw, unsigned* __restrict__ umask,
    float* __restrict__ acc) {
    int b = blockIdx.y;
    int a = blockIdx.x * 256 + threadIdx.x;
    float bce0_conf = 0.0f;
    if (a < A_TOT) {
        int hw, HW, W;
        float s;
        const float* base = lvl_base(a, b, p8, p16, p32, hw, HW, W, s);

        float tx = base[hw], ty = base[HW + hw];
        float tw = base[2 * HW + hw], th = base[3 * HW + hw];
        float cf = base[4 * HW + hw];
        int gx = hw % W, gy = hw / W;
        float pcx = (tx + (float)gx) * s;
        float pcy = (ty + (float)gy) * s;
        float pw = fexp2(tw * L2E) * s;
        float ph = fexp2(th * L2E) * s;

        // sigmoid(cf) and bce0(cf) sharing one exp
        float uc = fexp2(-cf * L2E);          // e^{-cf}
        float suc = 1.0f + uc;
        float sc = frcp(suc);
        bce0_conf = cf + LN2 * flog2(suc);    // log(1+e^cf)

        float suml1p = 0.0f, s0 = 0.0f;
        for (int c = 0; c < NC; c++) {
            float x = base[(5 + c) * HW + hw];
            float u = fexp2(-x * L2E);
            float su = 1.0f + u;
            float sx = frcp(su);
            s0 += x + LN2 * flog2(su);        // bce0(x)
            float pr = fsqrtf_(sx * sc);
            suml1p += fmaxf(LN2 * flog2(fmaxf(1.0f - pr, 1e-12f)), -100.0f);
        }

        // dval per gt: logp - log1mp at class gt_cls[b,g]
        for (int g = 0; g < NG; g++) {
            int c = gtc[b * NG + g];
            float x = base[(5 + c) * HW + hw];
            float u = fexp2(-x * L2E);
            float sx = frcp(1.0f + u);
            float pr = fsqrtf_(sx * sc);
            float lp  = fmaxf(LN2 * flog2(fmaxf(pr, 1e-12f)), -100.0f);
            float l1p = fmaxf(LN2 * flog2(fmaxf(1.0f - pr, 1e-12f)), -100.0f);
            dval[((size_t)(b * NG + g)) * A_TOT + a] = lp - l1p;
        }

        // union / inter masks
        float xc = ((float)gx + 0.5f) * s;
        float yc = ((float)gy + 0.5f) * s;
        unsigned m = 0;
        bool uni = false;
        float r = 2.5f * s;
        for (int g = 0; g < NG; g++) {
            float gcx = gtb[(b * NG + g) * 4 + 0];
            float gcy = gtb[(b * NG + g) * 4 + 1];
            float gw  = gtb[(b * NG + g) * 4 + 2];
            float gh  = gtb[(b * NG + g) * 4 + 3];
            bool ib = (xc > gcx - gw * 0.5f) && (gcx + gw * 0.5f > xc) &&
                      (yc > gcy - gh * 0.5f) && (gcy + gh * 0.5f > yc);
            bool im = (xc > gcx - r) && (gcx + r > xc) &&
                      (yc > gcy - r) && (gcy + r > yc);
            uni |= (ib || im);
            if (ib && im) m |= (1u << g);
        }
        if (uni) m |= (1u << 16);

        size_t i = (size_t)b * A_TOT + a;
        pbox[i] = make_float4(pcx, pcy, pw, ph);
        confw[i] = cf;
        sl1p[i] = suml1p;
        s0cls[i] = s0;
        umask[i] = m;
    }
    // wave-reduce bce0(conf) and atomically add
    float v = bce0_conf;
    for (int off = 32; off; off >>= 1) v += __shfl_down(v, off, 64);
    if ((threadIdx.x & 63) == 0) atomicAdd(&acc[0], v);
}

// ---------- kernel 2: per-(b,g) dual top-10 via register lists + tournament ----------
__global__ __launch_bounds__(256) void k2_assign(
    const float* __restrict__ gtb, const float4* __restrict__ pbox,
    const float* __restrict__ dval, const float* __restrict__ sl1p,
    const unsigned* __restrict__ umask, int* __restrict__ sel, int* __restrict__ nsel) {
    __shared__ unsigned long long wred[4];
    int blk = blockIdx.x;            // b*16+g
    int b = blk >> 4, g = blk & 15;
    int tid = threadIdx.x;

    float gcx = gtb[blk * 4 + 0], gcy = gtb[blk * 4 + 1];
    float gw = gtb[blk * 4 + 2],  gh = gtb[blk * 4 + 3];

    // per-thread sorted lists:
    unsigned long long topI[10];   // masked-iou keys, descending
    unsigned long long topC[10];   // cost keys, ascending
#pragma unroll
    for (int i = 0; i < 10; i++) { topI[i] = 0ull; topC[i] = 0xFFFFFFFFFFFFFFFFull; }

    for (int a = tid; a < A_TOT; a += 256) {
        float4 pb = pbox[(size_t)b * A_TOT + a];
        unsigned m = umask[(size_t)b * A_TOT + a];
        float iou = iou_cxcywh(gcx, gcy, gw, gh, pb.x, pb.y, pb.z, pb.w);
        float mi = ((m >> 16) & 1u) ? iou : 0.0f;
        float d = dval[(size_t)blk * A_TOT + a];
        float sp = sl1p[(size_t)b * A_TOT + a];
        float cost = cost_fast(iou, d, sp, m, g);

        unsigned long long kI = ((unsigned long long)__float_as_uint(mi) << 32) | (unsigned)a;
        if (kI > topI[9]) {
            unsigned long long v = kI;
#pragma unroll
            for (int i = 0; i < 10; i++) {
                unsigned long long big = umax64(topI[i], v);
                v = umin64(topI[i], v);
                topI[i] = big;
            }
        }
        unsigned long long kC = ((unsigned long long)__float_as_uint(cost) << 32) | (unsigned)a;
        if (kC < topC[9]) {
            unsigned long long v = kC;
#pragma unroll
            for (int i = 0; i < 10; i++) {
                unsigned long long sml = umin64(topC[i], v);
                v = umax64(topC[i], v);
                topC[i] = sml;
            }
        }
    }

    // ---- tournament 1: sum of global top-10 masked iou (descending) ----
    float ksum = 0.0f;
    for (int rr = 0; rr < 10; rr++) {
        unsigned long long h = topI[0];
        for (int off = 32; off; off >>= 1) h = umax64(h, __shfl_xor(h, off, 64));
        if ((tid & 63) == 0) wred[tid >> 6] = h;
        __syncthreads();
        unsigned long long w = umax64(umax64(wred[0], wred[1]), umax64(wred[2], wred[3]));
        ksum += __uint_as_float((unsigned)(w >> 32));
        if (topI[0] == w) {
#pragma unroll
            for (int i = 0; i < 9; i++) topI[i] = topI[i + 1];
            topI[9] = 0ull;
        }
        __syncthreads();
    }
    int dynk = (int)ksum;            // truncation matches astype(int32)
    if (dynk < 1) dynk = 1;
    if (dynk > 10) dynk = 10;

    // ---- tournament 2: 10 smallest costs (ascending, lowest-index ties) ----
    for (int rr = 0; rr < 10; rr++) {
        unsigned long long h = topC[0];
        for (int off = 32; off; off >>= 1) h = umin64(h, __shfl_xor(h, off, 64));
        if ((tid & 63) == 0) wred[tid >> 6] = h;
        __syncthreads();
        unsigned long long w = umin64(umin64(wred[0], wred[1]), umin64(wred[2], wred[3]));
        if (tid == 0) sel[blk * 10 + rr] = (int)(w & 0xffffffffu);
        if (topC[0] == w) {
#pragma unroll
            for (int i = 0; i < 9; i++) topC[i] = topC[i + 1];
            topC[9] = 0xFFFFFFFFFFFFFFFFull;
        }
        __syncthreads();
    }
    if (tid == 0) nsel[blk] = dynk;
}

// ---------- kernel 3: per-batch conflict resolution + fused loss partials ----------
__global__ __launch_bounds__(256) void k3_resolve(
    const float* __restrict__ gtb, const int* __restrict__ gtc,
    const float4* __restrict__ pbox, const float* __restrict__ dval,
    const float* __restrict__ sl1p, const unsigned* __restrict__ umask,
    const float* __restrict__ confw, const float* __restrict__ s0cls,
    const int* __restrict__ sel, const int* __restrict__ nsel,
    const float* __restrict__ p8, const float* __restrict__ p16, const float* __restrict__ p32,
    float* __restrict__ acc) {
    __shared__ unsigned tag[A_TOT];
    __shared__ float gb[NG * 4];
    __shared__ int gc[NG];
    __shared__ float red[256];
    int b = blockIdx.x, tid = threadIdx.x;

    for (int a = tid; a < A_TOT; a += 256) tag[a] = 0;
    if (tid < NG * 4) gb[tid] = gtb[b * NG * 4 + tid];
    if (tid < NG) gc[tid] = gtc[b * NG + tid];
    __syncthreads();

    if (tid < NG * 10) {
        int g = tid / 10, k = tid % 10;
        if (k < nsel[b * NG + g]) {
            int a = sel[(b * NG + g) * 10 + k];
            atomicAdd(&tag[a], 0x10000u + (unsigned)(g + 1));
        }
    }
    __syncthreads();

    float lbox = 0.0f, lconfc = 0.0f, lcls = 0.0f, nfg = 0.0f;
    for (int a = tid; a < A_TOT; a += 256) {
        unsigned t = tag[a];
        unsigned cnt = t >> 16;
        if (!cnt) continue;
        float4 pb = pbox[(size_t)b * A_TOT + a];
        int gs;
        if (cnt == 1) {
            gs = (int)(t & 0xffffu) - 1;
        } else {
            // argmin over all G of cost (first-min => lowest g on ties)
            unsigned m = umask[(size_t)b * A_TOT + a];
            float sp = sl1p[(size_t)b * A_TOT + a];
            float bc = 3.402823466e38f;
            gs = 0;
            for (int g = 0; g < NG; g++) {
                float iou = iou_cxcywh(gb[g * 4], gb[g * 4 + 1], gb[g * 4 + 2], gb[g * 4 + 3],
                                       pb.x, pb.y, pb.z, pb.w);
                float d = dval[((size_t)(b * NG + g)) * A_TOT + a];
                float c = cost_fast(iou, d, sp, m, g);
                if (c < bc) { bc = c; gs = g; }
            }
        }
        float miou = iou_cxcywh(gb[gs * 4], gb[gs * 4 + 1], gb[gs * 4 + 2], gb[gs * 4 + 3],
                                pb.x, pb.y, pb.z, pb.w);
        int cid = gc[gs];
        int hw, HW, W;
        float s;
        const float* base = lvl_base(a, b, p8, p16, p32, hw, HW, W, s);
        float xcid = base[(5 + cid) * HW + hw];

        lbox += 1.0f - miou * miou;
        lconfc -= confw[(size_t)b * A_TOT + a];
        lcls += s0cls[(size_t)b * A_TOT + a] - xcid * miou;
        nfg += 1.0f;
    }

    // block reduce the four partials
    float vals[4] = {lbox, lconfc, lcls, nfg};
    for (int i = 0; i < 4; i++) {
        red[tid] = vals[i];
        __syncthreads();
        for (int s2 = 128; s2 > 0; s2 >>= 1) {
            if (tid < s2) red[tid] += red[tid + s2];
            __syncthreads();
        }
        if (tid == 0) atomicAdd(&acc[1 + i], red[0]);
        __syncthreads();
    }
}

// ---------- kernel 4: final scalar ----------
__global__ void k4_final(const float* __restrict__ acc, float* __restrict__ out) {
    if (threadIdx.x == 0 && blockIdx.x == 0) {
        float nfg = acc[4];
        if (nfg < 1.0f) nfg = 1.0f;
        out[0] = (5.0f * acc[1] + (acc[0] + acc[2]) + acc[3]) / nfg;
    }
}

// ---------- launch ----------
extern "C" void kernel_launch(void* const* d_in, const int* in_sizes, int n_in,
                              void* d_out, int out_size, void* d_ws, size_t ws_size,
                              hipStream_t stream) {
    const float* p8  = (const float*)d_in[0];
    const float* p16 = (const float*)d_in[1];
    const float* p32 = (const float*)d_in[2];
    const float* gtb = (const float*)d_in[3];
    const int*   gtc = (const int*)d_in[4];

    char* w = (char*)d_ws;
    float4* pbox = (float4*)w;                 w += (size_t)NB * A_TOT * sizeof(float4);
    float* dval  = (float*)w;                  w += (size_t)NB * NG * A_TOT * sizeof(float);
    float* sl1p  = (float*)w;                  w += (size_t)NB * A_TOT * sizeof(float);
    float* s0c   = (float*)w;                  w += (size_t)NB * A_TOT * sizeof(float);
    float* conf  = (float*)w;                  w += (size_t)NB * A_TOT * sizeof(float);
    unsigned* um = (unsigned*)w;               w += (size_t)NB * A_TOT * sizeof(unsigned);
    int* sel     = (int*)w;                    w += (size_t)NB * NG * 10 * sizeof(int);
    int* nsel    = (int*)w;                    w += (size_t)NB * NG * sizeof(int);
    float* acc   = (float*)w;

    k0_zero<<<1, 64, 0, stream>>>(acc);
    k1_decode<<<dim3(33, NB), 256, 0, stream>>>(
        p8, p16, p32, gtb, gtc, pbox, dval, sl1p, s0c, conf, um, acc);
    k2_assign<<<NB * NG, 256, 0, stream>>>(gtb, pbox, dval, sl1p, um, sel, nsel);
    k3_resolve<<<NB, 256, 0, stream>>>(gtb, gtc, pbox, dval, sl1p, um, conf, s0c,
                                       sel, nsel, p8, p16, p32, acc);
    k4_final<<<1, 64, 0, stream>>>(acc, (float*)d_out);
}

// Round 3
// 238.163 us; speedup vs baseline: 1.4747x; 1.0452x over previous
//
#include <hip/hip_runtime.h>
#include <hip/hip_bf16.h>

#define A_TOT 8400
#define NB 32
#define NG 16
#define NC 80

#define L2E 1.44269504088896340736f
#define LN2 0.69314718055994530942f

// ---------- fast native transcendentals ----------
__device__ inline float fexp2(float x) { return __builtin_amdgcn_exp2f(x); }
__device__ inline float flog2(float x) { return __builtin_amdgcn_logf(x); }
__device__ inline float frcp(float x)  { return __builtin_amdgcn_rcpf(x); }
__device__ inline float fsqrtf_(float x) { return __builtin_amdgcn_sqrtf(x); }

__device__ inline float iou_cxcywh(float acx, float acy, float aw, float ah,
                                   float bcx, float bcy, float bw, float bh) {
    float tlx = fmaxf(acx - aw * 0.5f, bcx - bw * 0.5f);
    float tly = fmaxf(acy - ah * 0.5f, bcy - bh * 0.5f);
    float brx = fminf(acx + aw * 0.5f, bcx + bw * 0.5f);
    float bry = fminf(acy + ah * 0.5f, bcy + bh * 0.5f);
    float w = fmaxf(brx - tlx, 0.0f);
    float h = fmaxf(bry - tly, 0.0f);
    float inter = w * h;
    return inter / (aw * ah + bw * bh - inter + 1e-16f);
}

// d = logp - log1mp for class logit x and conf-sigmoid sc  (shared by k2/k3 -> consistent)
__device__ inline float dval_of(float x, float sc) {
    float u = fexp2(-x * L2E);
    float sx = frcp(1.0f + u);
    float pr = fsqrtf_(sx * sc);
    float lp  = fmaxf(LN2 * flog2(fmaxf(pr, 1e-12f)), -100.0f);
    float l1p = fmaxf(LN2 * flog2(fmaxf(1.0f - pr, 1e-12f)), -100.0f);
    return lp - l1p;
}

// cost for (g, a); m = umask word (bit16 = union, bits0..15 = inter per g)
__device__ inline float cost_fast(float iou, float d, float sp, unsigned m, int g) {
    if (!((m >> 16) & 1u)) return 1e15f;
    float c = -(d + sp) - 3.0f * LN2 * flog2(iou + 1e-8f);
    if (!((m >> g) & 1u)) c += 100000.0f;
    return c;
}

__device__ inline unsigned long long umax64(unsigned long long a, unsigned long long b) {
    return a > b ? a : b;
}
__device__ inline unsigned long long umin64(unsigned long long a, unsigned long long b) {
    return a < b ? a : b;
}

// resolve anchor index -> level base / hw / HW / W / stride
__device__ inline const float* lvl_base(int a, int b, const float* p8, const float* p16,
                                        const float* p32, int& hw, int& HW, int& W, float& s) {
    if (a < 6400) { hw = a;        HW = 6400; W = 80; s = 8.0f;  return p8  + (size_t)b * 85 * 6400; }
    if (a < 8000) { hw = a - 6400; HW = 1600; W = 40; s = 16.0f; return p16 + (size_t)b * 85 * 1600; }
    { hw = a - 8000; HW = 400; W = 20; s = 32.0f; return p32 + (size_t)b * 85 * 400; }
}

// ---------- kernel 0: zero accumulators ----------
__global__ void k0_zero(float* acc) {
    if (threadIdx.x < 8) acc[threadIdx.x] = 0.0f;
}

// ---------- kernel 1: decode + per-anchor stats (ILP-unrolled class loop) ----------
__global__ __launch_bounds__(256) void k1_decode(
    const float* __restrict__ p8, const float* __restrict__ p16, const float* __restrict__ p32,
    const float* __restrict__ gtb,
    float4* __restrict__ pbox, float* __restrict__ sl1p,
    float* __restrict__ s0cls, float* __restrict__ confw, unsigned* __restrict__ umask,
    float* __restrict__ acc) {
    int b = blockIdx.y;
    int a = blockIdx.x * 256 + threadIdx.x;
    float bce0_conf = 0.0f;
    if (a < A_TOT) {
        int hw, HW, W;
        float s;
        const float* base = lvl_base(a, b, p8, p16, p32, hw, HW, W, s);

        float tx = base[hw], ty = base[HW + hw];
        float tw = base[2 * HW + hw], th = base[3 * HW + hw];
        float cf = base[4 * HW + hw];
        int gx = hw % W, gy = hw / W;
        float pcx = (tx + (float)gx) * s;
        float pcy = (ty + (float)gy) * s;
        float pw = fexp2(tw * L2E) * s;
        float ph = fexp2(th * L2E) * s;

        // sigmoid(cf) and bce0(cf) sharing one exp
        float uc = fexp2(-cf * L2E);          // e^{-cf}
        float suc = 1.0f + uc;
        float sc = frcp(suc);
        bce0_conf = cf + LN2 * flog2(suc);    // log(1+e^cf)

        float suml1p = 0.0f, s0 = 0.0f;
        const float* cbase = base + 5 * HW + hw;
#pragma unroll
        for (int cc = 0; cc < NC; cc += 16) {
            float x[16];
#pragma unroll
            for (int j = 0; j < 16; j++) x[j] = cbase[(cc + j) * HW];
#pragma unroll
            for (int j = 0; j < 16; j++) {
                float u = fexp2(-x[j] * L2E);
                float su = 1.0f + u;
                s0 += x[j] + LN2 * flog2(su);                 // bce0(x)
                float pr = fsqrtf_(frcp(su) * sc);
                suml1p += fmaxf(LN2 * flog2(fmaxf(1.0f - pr, 1e-12f)), -100.0f);
            }
        }

        // union / inter masks
        float xc = ((float)gx + 0.5f) * s;
        float yc = ((float)gy + 0.5f) * s;
        unsigned m = 0;
        bool uni = false;
        float r = 2.5f * s;
#pragma unroll 4
        for (int g = 0; g < NG; g++) {
            float gcx = gtb[(b * NG + g) * 4 + 0];
            float gcy = gtb[(b * NG + g) * 4 + 1];
            float gw  = gtb[(b * NG + g) * 4 + 2];
            float gh  = gtb[(b * NG + g) * 4 + 3];
            bool ib = (xc > gcx - gw * 0.5f) && (gcx + gw * 0.5f > xc) &&
                      (yc > gcy - gh * 0.5f) && (gcy + gh * 0.5f > yc);
            bool im = (xc > gcx - r) && (gcx + r > xc) &&
                      (yc > gcy - r) && (gcy + r > yc);
            uni |= (ib || im);
            if (ib && im) m |= (1u << g);
        }
        if (uni) m |= (1u << 16);

        size_t i = (size_t)b * A_TOT + a;
        pbox[i] = make_float4(pcx, pcy, pw, ph);
        confw[i] = cf;
        sl1p[i] = suml1p;
        s0cls[i] = s0;
        umask[i] = m;
    }
    // wave-reduce bce0(conf) and atomically add
    float v = bce0_conf;
    for (int off = 32; off; off >>= 1) v += __shfl_down(v, off, 64);
    if ((threadIdx.x & 63) == 0) atomicAdd(&acc[0], v);
}

// ---------- kernel 2: per-(b,g) dual top-10 via register lists + tournament ----------
__global__ __launch_bounds__(256) void k2_assign(
    const float* __restrict__ gtb, const int* __restrict__ gtc,
    const float4* __restrict__ pbox, const float* __restrict__ sl1p,
    const float* __restrict__ confw, const unsigned* __restrict__ umask,
    const float* __restrict__ p8, const float* __restrict__ p16, const float* __restrict__ p32,
    int* __restrict__ sel, int* __restrict__ nsel) {
    __shared__ unsigned long long wred[4];
    int blk = blockIdx.x;            // b*16+g
    int b = blk >> 4, g = blk & 15;
    int tid = threadIdx.x;

    float gcx = gtb[blk * 4 + 0], gcy = gtb[blk * 4 + 1];
    float gw = gtb[blk * 4 + 2],  gh = gtb[blk * 4 + 3];
    int cg = gtc[blk];               // block-uniform class id

    // per-thread sorted lists:
    unsigned long long topI[10];   // masked-iou keys, descending
    unsigned long long topC[10];   // cost keys, ascending
#pragma unroll
    for (int i = 0; i < 10; i++) { topI[i] = 0ull; topC[i] = 0xFFFFFFFFFFFFFFFFull; }

    for (int a = tid; a < A_TOT; a += 256) {
        size_t i = (size_t)b * A_TOT + a;
        float4 pb = pbox[i];
        unsigned m = umask[i];
        float iou = iou_cxcywh(gcx, gcy, gw, gh, pb.x, pb.y, pb.z, pb.w);
        float mi = ((m >> 16) & 1u) ? iou : 0.0f;

        int hw, HW, W;
        float s;
        const float* base = lvl_base(a, b, p8, p16, p32, hw, HW, W, s);
        float x = base[(5 + cg) * HW + hw];
        float cf = confw[i];
        float sc = frcp(1.0f + fexp2(-cf * L2E));
        float d = dval_of(x, sc);
        float sp = sl1p[i];
        float cost = cost_fast(iou, d, sp, m, g);

        unsigned long long kI = ((unsigned long long)__float_as_uint(mi) << 32) | (unsigned)a;
        if (kI > topI[9]) {
            unsigned long long v = kI;
#pragma unroll
            for (int i2 = 0; i2 < 10; i2++) {
                unsigned long long big = umax64(topI[i2], v);
                v = umin64(topI[i2], v);
                topI[i2] = big;
            }
        }
        unsigned long long kC = ((unsigned long long)__float_as_uint(cost) << 32) | (unsigned)a;
        if (kC < topC[9]) {
            unsigned long long v = kC;
#pragma unroll
            for (int i2 = 0; i2 < 10; i2++) {
                unsigned long long sml = umin64(topC[i2], v);
                v = umax64(topC[i2], v);
                topC[i2] = sml;
            }
        }
    }

    // ---- tournament 1: sum of global top-10 masked iou (descending) ----
    float ksum = 0.0f;
    for (int rr = 0; rr < 10; rr++) {
        unsigned long long h = topI[0];
        for (int off = 32; off; off >>= 1) h = umax64(h, __shfl_xor(h, off, 64));
        if ((tid & 63) == 0) wred[tid >> 6] = h;
        __syncthreads();
        unsigned long long w = umax64(umax64(wred[0], wred[1]), umax64(wred[2], wred[3]));
        ksum += __uint_as_float((unsigned)(w >> 32));
        if (topI[0] == w) {
#pragma unroll
            for (int i = 0; i < 9; i++) topI[i] = topI[i + 1];
            topI[9] = 0ull;
        }
        __syncthreads();
    }
    int dynk = (int)ksum;            // truncation matches astype(int32)
    if (dynk < 1) dynk = 1;
    if (dynk > 10) dynk = 10;

    // ---- tournament 2: 10 smallest costs (ascending, lowest-index ties) ----
    for (int rr = 0; rr < 10; rr++) {
        unsigned long long h = topC[0];
        for (int off = 32; off; off >>= 1) h = umin64(h, __shfl_xor(h, off, 64));
        if ((tid & 63) == 0) wred[tid >> 6] = h;
        __syncthreads();
        unsigned long long w = umin64(umin64(wred[0], wred[1]), umin64(wred[2], wred[3]));
        if (tid == 0) sel[blk * 10 + rr] = (int)(w & 0xffffffffu);
        if (topC[0] == w) {
#pragma unroll
            for (int i = 0; i < 9; i++) topC[i] = topC[i + 1];
            topC[9] = 0xFFFFFFFFFFFFFFFFull;
        }
        __syncthreads();
    }
    if (tid == 0) nsel[blk] = dynk;
}

// ---------- kernel 3: per-batch conflict resolution + fused loss partials ----------
__global__ __launch_bounds__(256) void k3_resolve(
    const float* __restrict__ gtb, const int* __restrict__ gtc,
    const float4* __restrict__ pbox, const float* __restrict__ sl1p,
    const unsigned* __restrict__ umask,
    const float* __restrict__ confw, const float* __restrict__ s0cls,
    const int* __restrict__ sel, const int* __restrict__ nsel,
    const float* __restrict__ p8, const float* __restrict__ p16, const float* __restrict__ p32,
    float* __restrict__ acc) {
    __shared__ unsigned tag[A_TOT];
    __shared__ float gb[NG * 4];
    __shared__ int gc[NG];
    __shared__ float red[256];
    int b = blockIdx.x, tid = threadIdx.x;

    for (int a = tid; a < A_TOT; a += 256) tag[a] = 0;
    if (tid < NG * 4) gb[tid] = gtb[b * NG * 4 + tid];
    if (tid < NG) gc[tid] = gtc[b * NG + tid];
    __syncthreads();

    if (tid < NG * 10) {
        int g = tid / 10, k = tid % 10;
        if (k < nsel[b * NG + g]) {
            int a = sel[(b * NG + g) * 10 + k];
            atomicAdd(&tag[a], 0x10000u + (unsigned)(g + 1));
        }
    }
    __syncthreads();

    float lbox = 0.0f, lconfc = 0.0f, lcls = 0.0f, nfg = 0.0f;
    for (int a = tid; a < A_TOT; a += 256) {
        unsigned t = tag[a];
        unsigned cnt = t >> 16;
        if (!cnt) continue;
        size_t i = (size_t)b * A_TOT + a;
        float4 pb = pbox[i];
        int hw, HW, W;
        float s;
        const float* base = lvl_base(a, b, p8, p16, p32, hw, HW, W, s);
        float cf = confw[i];
        int gs;
        if (cnt == 1) {
            gs = (int)(t & 0xffffu) - 1;
        } else {
            // argmin over all G of cost (first-min => lowest g on ties)
            unsigned m = umask[i];
            float sp = sl1p[i];
            float sc = frcp(1.0f + fexp2(-cf * L2E));
            float bc = 3.402823466e38f;
            gs = 0;
            for (int g = 0; g < NG; g++) {
                float iou = iou_cxcywh(gb[g * 4], gb[g * 4 + 1], gb[g * 4 + 2], gb[g * 4 + 3],
                                       pb.x, pb.y, pb.z, pb.w);
                float x = base[(5 + gc[g]) * HW + hw];
                float d = dval_of(x, sc);
                float c = cost_fast(iou, d, sp, m, g);
                if (c < bc) { bc = c; gs = g; }
            }
        }
        float miou = iou_cxcywh(gb[gs * 4], gb[gs * 4 + 1], gb[gs * 4 + 2], gb[gs * 4 + 3],
                                pb.x, pb.y, pb.z, pb.w);
        int cid = gc[gs];
        float xcid = base[(5 + cid) * HW + hw];

        lbox += 1.0f - miou * miou;
        lconfc -= cf;
        lcls += s0cls[i] - xcid * miou;
        nfg += 1.0f;
    }

    // block reduce the four partials
    float vals[4] = {lbox, lconfc, lcls, nfg};
    for (int i = 0; i < 4; i++) {
        red[tid] = vals[i];
        __syncthreads();
        for (int s2 = 128; s2 > 0; s2 >>= 1) {
            if (tid < s2) red[tid] += red[tid + s2];
            __syncthreads();
        }
        if (tid == 0) atomicAdd(&acc[1 + i], red[0]);
        __syncthreads();
    }
}

// ---------- kernel 4: final scalar ----------
__global__ void k4_final(const float* __restrict__ acc, float* __restrict__ out) {
    if (threadIdx.x == 0 && blockIdx.x == 0) {
        float nfg = acc[4];
        if (nfg < 1.0f) nfg = 1.0f;
        out[0] = (5.0f * acc[1] + (acc[0] + acc[2]) + acc[3]) / nfg;
    }
}

// ---------- launch ----------
extern "C" void kernel_launch(void* const* d_in, const int* in_sizes, int n_in,
                              void* d_out, int out_size, void* d_ws, size_t ws_size,
                              hipStream_t stream) {
    const float* p8  = (const float*)d_in[0];
    const float* p16 = (const float*)d_in[1];
    const float* p32 = (const float*)d_in[2];
    const float* gtb = (const float*)d_in[3];
    const int*   gtc = (const int*)d_in[4];

    char* w = (char*)d_ws;
    float4* pbox = (float4*)w;                 w += (size_t)NB * A_TOT * sizeof(float4);
    float* sl1p  = (float*)w;                  w += (size_t)NB * A_TOT * sizeof(float);
    float* s0c   = (float*)w;                  w += (size_t)NB * A_TOT * sizeof(float);
    float* conf  = (float*)w;                  w += (size_t)NB * A_TOT * sizeof(float);
    unsigned* um = (unsigned*)w;               w += (size_t)NB * A_TOT * sizeof(unsigned);
    int* sel     = (int*)w;                    w += (size_t)NB * NG * 10 * sizeof(int);
    int* nsel    = (int*)w;                    w += (size_t)NB * NG * sizeof(int);
    float* acc   = (float*)w;

    k0_zero<<<1, 64, 0, stream>>>(acc);
    k1_decode<<<dim3(33, NB), 256, 0, stream>>>(
        p8, p16, p32, gtb, pbox, sl1p, s0c, conf, um, acc);
    k2_assign<<<NB * NG, 256, 0, stream>>>(gtb, gtc, pbox, sl1p, conf, um,
                                           p8, p16, p32, sel, nsel);
    k3_resolve<<<NB, 256, 0, stream>>>(gtb, gtc, pbox, sl1p, um, conf, s0c,
                                       sel, nsel, p8, p16, p32, acc);
    k4_final<<<1, 64, 0, stream>>>(acc, (float*)d_out);
}

// Round 4
// 209.031 us; speedup vs baseline: 1.6802x; 1.1394x over previous
//
#include <hip/hip_runtime.h>
#include <hip/hip_bf16.h>

#define A_TOT 8400
#define NB 32
#define NG 16
#define NC 80

#define K1_GX 132                 // ceil(8400/64) anchors-per-block=64
#define NWAVE (K1_GX * NB * 4)    // per-wave conf partials

#define L2E 1.44269504088896340736f
#define LN2 0.69314718055994530942f

// ---------- fast native transcendentals ----------
__device__ inline float fexp2(float x) { return __builtin_amdgcn_exp2f(x); }
__device__ inline float flog2(float x) { return __builtin_amdgcn_logf(x); }
__device__ inline float frcp(float x)  { return __builtin_amdgcn_rcpf(x); }
__device__ inline float fsqrtf_(float x) { return __builtin_amdgcn_sqrtf(x); }

__device__ inline float iou_cxcywh(float acx, float acy, float aw, float ah,
                                   float bcx, float bcy, float bw, float bh) {
    float tlx = fmaxf(acx - aw * 0.5f, bcx - bw * 0.5f);
    float tly = fmaxf(acy - ah * 0.5f, bcy - bh * 0.5f);
    float brx = fminf(acx + aw * 0.5f, bcx + bw * 0.5f);
    float bry = fminf(acy + ah * 0.5f, bcy + bh * 0.5f);
    float w = fmaxf(brx - tlx, 0.0f);
    float h = fmaxf(bry - tly, 0.0f);
    float inter = w * h;
    return inter / (aw * ah + bw * bh - inter + 1e-16f);
}

// d = logp - log1mp for class logit x and conf-sigmoid sc  (shared by k2/k3 -> consistent)
__device__ inline float dval_of(float x, float sc) {
    float u = fexp2(-x * L2E);
    float sx = frcp(1.0f + u);
    float pr = fsqrtf_(sx * sc);
    float lp  = fmaxf(LN2 * flog2(fmaxf(pr, 1e-12f)), -100.0f);
    float l1p = fmaxf(LN2 * flog2(fmaxf(1.0f - pr, 1e-12f)), -100.0f);
    return lp - l1p;
}

// cost for (g, a); m = umask word (bit16 = union, bits0..15 = inter per g)
__device__ inline float cost_fast(float iou, float d, float sp, unsigned m, int g) {
    if (!((m >> 16) & 1u)) return 1e15f;
    float c = -(d + sp) - 3.0f * LN2 * flog2(iou + 1e-8f);
    if (!((m >> g) & 1u)) c += 100000.0f;
    return c;
}

__device__ inline unsigned long long umax64(unsigned long long a, unsigned long long b) {
    return a > b ? a : b;
}
__device__ inline unsigned long long umin64(unsigned long long a, unsigned long long b) {
    return a < b ? a : b;
}

// resolve anchor index -> level base / hw / HW / W / stride
__device__ inline const float* lvl_base(int a, int b, const float* p8, const float* p16,
                                        const float* p32, int& hw, int& HW, int& W, float& s) {
    if (a < 6400) { hw = a;        HW = 6400; W = 80; s = 8.0f;  return p8  + (size_t)b * 85 * 6400; }
    if (a < 8000) { hw = a - 6400; HW = 1600; W = 40; s = 16.0f; return p16 + (size_t)b * 85 * 1600; }
    { hw = a - 8000; HW = 400; W = 20; s = 32.0f; return p32 + (size_t)b * 85 * 400; }
}

// ---------- kernel 0: zero accumulators ----------
__global__ void k0_zero(float* acc) {
    if (threadIdx.x < 8) acc[threadIdx.x] = 0.0f;
}

// ---------- kernel 1: decode + per-anchor stats ----------
// 4 lanes per anchor (20 classes each), grid dim3(132, NB), no global atomics.
__global__ __launch_bounds__(256) void k1_decode(
    const float* __restrict__ p8, const float* __restrict__ p16, const float* __restrict__ p32,
    const float* __restrict__ gtb,
    float4* __restrict__ pbox, float* __restrict__ sl1p,
    float* __restrict__ s0cls, float* __restrict__ confw, float* __restrict__ ssc,
    unsigned* __restrict__ umask, float* __restrict__ part) {
    int b = blockIdx.y;
    int tid = threadIdx.x;
    int a = blockIdx.x * 64 + (tid >> 2);
    int quad = tid & 3;
    float bce0_conf = 0.0f;
    if (a < A_TOT) {
        int hw, HW, W;
        float s;
        const float* base = lvl_base(a, b, p8, p16, p32, hw, HW, W, s);

        float cf = base[4 * HW + hw];
        float uc = fexp2(-cf * L2E);          // e^{-cf}
        float suc = 1.0f + uc;
        float sc = frcp(suc);

        // 20-class chunk per lane, loads batched for ILP
        const float* cbase = base + (5 + quad * 20) * HW + hw;
        float x[20];
#pragma unroll
        for (int j = 0; j < 20; j++) x[j] = cbase[j * HW];
        float s0 = 0.0f, suml1p = 0.0f;
#pragma unroll
        for (int j = 0; j < 20; j++) {
            float u = fexp2(-x[j] * L2E);
            float su = 1.0f + u;
            s0 += x[j] + LN2 * flog2(su);                 // bce0(x)
            float pr = fsqrtf_(frcp(su) * sc);
            suml1p += fmaxf(LN2 * flog2(fmaxf(1.0f - pr, 1e-12f)), -100.0f);
        }
        // combine within quad
        s0 += __shfl_xor(s0, 1, 64);
        s0 += __shfl_xor(s0, 2, 64);
        suml1p += __shfl_xor(suml1p, 1, 64);
        suml1p += __shfl_xor(suml1p, 2, 64);

        if (quad == 0) {
            float tx = base[hw], ty = base[HW + hw];
            float tw = base[2 * HW + hw], th = base[3 * HW + hw];
            int gx = hw % W, gy = hw / W;
            float pcx = (tx + (float)gx) * s;
            float pcy = (ty + (float)gy) * s;
            float pw = fexp2(tw * L2E) * s;
            float ph = fexp2(th * L2E) * s;

            bce0_conf = cf + LN2 * flog2(suc);   // log(1+e^cf)

            // union / inter masks
            float xc = ((float)gx + 0.5f) * s;
            float yc = ((float)gy + 0.5f) * s;
            unsigned m = 0;
            bool uni = false;
            float r = 2.5f * s;
#pragma unroll 4
            for (int g = 0; g < NG; g++) {
                float gcx = gtb[(b * NG + g) * 4 + 0];
                float gcy = gtb[(b * NG + g) * 4 + 1];
                float gw  = gtb[(b * NG + g) * 4 + 2];
                float gh  = gtb[(b * NG + g) * 4 + 3];
                bool ib = (xc > gcx - gw * 0.5f) && (gcx + gw * 0.5f > xc) &&
                          (yc > gcy - gh * 0.5f) && (gcy + gh * 0.5f > yc);
                bool im = (xc > gcx - r) && (gcx + r > xc) &&
                          (yc > gcy - r) && (gcy + r > yc);
                uni |= (ib || im);
                if (ib && im) m |= (1u << g);
            }
            if (uni) m |= (1u << 16);

            size_t i = (size_t)b * A_TOT + a;
            pbox[i] = make_float4(pcx, pcy, pw, ph);
            confw[i] = cf;
            ssc[i] = sc;
            sl1p[i] = suml1p;
            s0cls[i] = s0;
            umask[i] = m;
        }
    }
    // wave-reduce bce0(conf), one store per wave (no atomics)
    float v = bce0_conf;
    for (int off = 32; off; off >>= 1) v += __shfl_down(v, off, 64);
    if ((tid & 63) == 0) {
        int wave = (blockIdx.y * gridDim.x + blockIdx.x) * 4 + (tid >> 6);
        part[wave] = v;
    }
}

// ---------- kernel 2: per-(b,g) dual top-10 via register lists + tournament ----------
__global__ __launch_bounds__(256) void k2_assign(
    const float* __restrict__ gtb, const int* __restrict__ gtc,
    const float4* __restrict__ pbox, const float* __restrict__ sl1p,
    const float* __restrict__ ssc, const unsigned* __restrict__ umask,
    const float* __restrict__ p8, const float* __restrict__ p16, const float* __restrict__ p32,
    int* __restrict__ sel, int* __restrict__ nsel) {
    __shared__ unsigned long long wred[4];
    int blk = blockIdx.x;            // b*16+g
    int b = blk >> 4, g = blk & 15;
    int tid = threadIdx.x;

    float gcx = gtb[blk * 4 + 0], gcy = gtb[blk * 4 + 1];
    float gw = gtb[blk * 4 + 2],  gh = gtb[blk * 4 + 3];
    int cg = gtc[blk];               // block-uniform class id

    // per-thread sorted lists:
    unsigned long long topI[10];   // masked-iou keys, descending
    unsigned long long topC[10];   // cost keys, ascending
#pragma unroll
    for (int i = 0; i < 10; i++) { topI[i] = 0ull; topC[i] = 0xFFFFFFFFFFFFFFFFull; }

    for (int a = tid; a < A_TOT; a += 256) {
        size_t i = (size_t)b * A_TOT + a;
        float4 pb = pbox[i];
        unsigned m = umask[i];
        float iou = iou_cxcywh(gcx, gcy, gw, gh, pb.x, pb.y, pb.z, pb.w);
        float mi = ((m >> 16) & 1u) ? iou : 0.0f;

        int hw, HW, W;
        float s;
        const float* base = lvl_base(a, b, p8, p16, p32, hw, HW, W, s);
        float x = base[(5 + cg) * HW + hw];
        float sc = ssc[i];
        float d = dval_of(x, sc);
        float sp = sl1p[i];
        float cost = cost_fast(iou, d, sp, m, g);

        if (mi > 0.0f) {
            unsigned long long kI = ((unsigned long long)__float_as_uint(mi) << 32) | (unsigned)a;
            if (kI > topI[9]) {
                unsigned long long v = kI;
#pragma unroll
                for (int i2 = 0; i2 < 10; i2++) {
                    unsigned long long big = umax64(topI[i2], v);
                    v = umin64(topI[i2], v);
                    topI[i2] = big;
                }
            }
        }
        unsigned long long kC = ((unsigned long long)__float_as_uint(cost) << 32) | (unsigned)a;
        if (kC < topC[9]) {
            unsigned long long v = kC;
#pragma unroll
            for (int i2 = 0; i2 < 10; i2++) {
                unsigned long long sml = umin64(topC[i2], v);
                v = umax64(topC[i2], v);
                topC[i2] = sml;
            }
        }
    }

    // ---- tournament 1: sum of global top-10 masked iou (descending) ----
    float ksum = 0.0f;
    for (int rr = 0; rr < 10; rr++) {
        unsigned long long h = topI[0];
        for (int off = 32; off; off >>= 1) h = umax64(h, __shfl_xor(h, off, 64));
        if ((tid & 63) == 0) wred[tid >> 6] = h;
        __syncthreads();
        unsigned long long w = umax64(umax64(wred[0], wred[1]), umax64(wred[2], wred[3]));
        ksum += __uint_as_float((unsigned)(w >> 32));
        if (topI[0] == w) {
#pragma unroll
            for (int i = 0; i < 9; i++) topI[i] = topI[i + 1];
            topI[9] = 0ull;
        }
        __syncthreads();
    }
    int dynk = (int)ksum;            // truncation matches astype(int32)
    if (dynk < 1) dynk = 1;
    if (dynk > 10) dynk = 10;

    // ---- tournament 2: 10 smallest costs (ascending, lowest-index ties) ----
    for (int rr = 0; rr < 10; rr++) {
        unsigned long long h = topC[0];
        for (int off = 32; off; off >>= 1) h = umin64(h, __shfl_xor(h, off, 64));
        if ((tid & 63) == 0) wred[tid >> 6] = h;
        __syncthreads();
        unsigned long long w = umin64(umin64(wred[0], wred[1]), umin64(wred[2], wred[3]));
        if (tid == 0) sel[blk * 10 + rr] = (int)(w & 0xffffffffu);
        if (topC[0] == w) {
#pragma unroll
            for (int i = 0; i < 9; i++) topC[i] = topC[i + 1];
            topC[9] = 0xFFFFFFFFFFFFFFFFull;
        }
        __syncthreads();
    }
    if (tid == 0) nsel[blk] = dynk;
}

// ---------- kernel 3: per-batch conflict resolution + fused loss partials ----------
__global__ __launch_bounds__(256) void k3_resolve(
    const float* __restrict__ gtb, const int* __restrict__ gtc,
    const float4* __restrict__ pbox, const float* __restrict__ sl1p,
    const unsigned* __restrict__ umask,
    const float* __restrict__ confw, const float* __restrict__ ssc,
    const float* __restrict__ s0cls,
    const int* __restrict__ sel, const int* __restrict__ nsel,
    const float* __restrict__ p8, const float* __restrict__ p16, const float* __restrict__ p32,
    float* __restrict__ acc) {
    __shared__ unsigned tag[A_TOT];
    __shared__ float gb[NG * 4];
    __shared__ int gc[NG];
    __shared__ float red[256];
    int b = blockIdx.x, tid = threadIdx.x;

    for (int a = tid; a < A_TOT; a += 256) tag[a] = 0;
    if (tid < NG * 4) gb[tid] = gtb[b * NG * 4 + tid];
    if (tid < NG) gc[tid] = gtc[b * NG + tid];
    __syncthreads();

    if (tid < NG * 10) {
        int g = tid / 10, k = tid % 10;
        if (k < nsel[b * NG + g]) {
            int a = sel[(b * NG + g) * 10 + k];
            atomicAdd(&tag[a], 0x10000u + (unsigned)(g + 1));
        }
    }
    __syncthreads();

    float lbox = 0.0f, lconfc = 0.0f, lcls = 0.0f, nfg = 0.0f;
    for (int a = tid; a < A_TOT; a += 256) {
        unsigned t = tag[a];
        unsigned cnt = t >> 16;
        if (!cnt) continue;
        size_t i = (size_t)b * A_TOT + a;
        float4 pb = pbox[i];
        int hw, HW, W;
        float s;
        const float* base = lvl_base(a, b, p8, p16, p32, hw, HW, W, s);
        int gs;
        if (cnt == 1) {
            gs = (int)(t & 0xffffu) - 1;
        } else {
            // argmin over all G of cost (first-min => lowest g on ties)
            unsigned m = umask[i];
            float sp = sl1p[i];
            float sc = ssc[i];
            float bc = 3.402823466e38f;
            gs = 0;
            for (int g = 0; g < NG; g++) {
                float iou = iou_cxcywh(gb[g * 4], gb[g * 4 + 1], gb[g * 4 + 2], gb[g * 4 + 3],
                                       pb.x, pb.y, pb.z, pb.w);
                float x = base[(5 + gc[g]) * HW + hw];
                float d = dval_of(x, sc);
                float c = cost_fast(iou, d, sp, m, g);
                if (c < bc) { bc = c; gs = g; }
            }
        }
        float miou = iou_cxcywh(gb[gs * 4], gb[gs * 4 + 1], gb[gs * 4 + 2], gb[gs * 4 + 3],
                                pb.x, pb.y, pb.z, pb.w);
        int cid = gc[gs];
        float xcid = base[(5 + cid) * HW + hw];

        lbox += 1.0f - miou * miou;
        lconfc -= confw[i];
        lcls += s0cls[i] - xcid * miou;
        nfg += 1.0f;
    }

    // block reduce the four partials
    float vals[4] = {lbox, lconfc, lcls, nfg};
    for (int i = 0; i < 4; i++) {
        red[tid] = vals[i];
        __syncthreads();
        for (int s2 = 128; s2 > 0; s2 >>= 1) {
            if (tid < s2) red[tid] += red[tid + s2];
            __syncthreads();
        }
        if (tid == 0) atomicAdd(&acc[1 + i], red[0]);
        __syncthreads();
    }
}

// ---------- kernel 4: sum conf partials + final scalar ----------
__global__ __launch_bounds__(256) void k4_final(
    const float* __restrict__ part, const float* __restrict__ acc, float* __restrict__ out) {
    __shared__ float red[256];
    int tid = threadIdx.x;
    float v = 0.0f;
    for (int i = tid; i < NWAVE; i += 256) v += part[i];
    red[tid] = v;
    __syncthreads();
    for (int s2 = 128; s2 > 0; s2 >>= 1) {
        if (tid < s2) red[tid] += red[tid + s2];
        __syncthreads();
    }
    if (tid == 0) {
        float nfg = acc[4];
        if (nfg < 1.0f) nfg = 1.0f;
        out[0] = (5.0f * acc[1] + (red[0] + acc[2]) + acc[3]) / nfg;
    }
}

// ---------- launch ----------
extern "C" void kernel_launch(void* const* d_in, const int* in_sizes, int n_in,
                              void* d_out, int out_size, void* d_ws, size_t ws_size,
                              hipStream_t stream) {
    const float* p8  = (const float*)d_in[0];
    const float* p16 = (const float*)d_in[1];
    const float* p32 = (const float*)d_in[2];
    const float* gtb = (const float*)d_in[3];
    const int*   gtc = (const int*)d_in[4];

    char* w = (char*)d_ws;
    float4* pbox = (float4*)w;                 w += (size_t)NB * A_TOT * sizeof(float4);
    float* sl1p  = (float*)w;                  w += (size_t)NB * A_TOT * sizeof(float);
    float* s0c   = (float*)w;                  w += (size_t)NB * A_TOT * sizeof(float);
    float* conf  = (float*)w;                  w += (size_t)NB * A_TOT * sizeof(float);
    float* sscp  = (float*)w;                  w += (size_t)NB * A_TOT * sizeof(float);
    unsigned* um = (unsigned*)w;               w += (size_t)NB * A_TOT * sizeof(unsigned);
    int* sel     = (int*)w;                    w += (size_t)NB * NG * 10 * sizeof(int);
    int* nsel    = (int*)w;                    w += (size_t)NB * NG * sizeof(int);
    float* part  = (float*)w;                  w += (size_t)NWAVE * sizeof(float);
    float* acc   = (float*)w;

    k0_zero<<<1, 64, 0, stream>>>(acc);
    k1_decode<<<dim3(K1_GX, NB), 256, 0, stream>>>(
        p8, p16, p32, gtb, pbox, sl1p, s0c, conf, sscp, um, part);
    k2_assign<<<NB * NG, 256, 0, stream>>>(gtb, gtc, pbox, sl1p, sscp, um,
                                           p8, p16, p32, sel, nsel);
    k3_resolve<<<NB, 256, 0, stream>>>(gtb, gtc, pbox, sl1p, um, conf, sscp, s0c,
                                       sel, nsel, p8, p16, p32, acc);
    k4_final<<<1, 256, 0, stream>>>(part, acc, (float*)d_out);
}